// Round 6
// baseline (296.028 us; speedup 1.0000x reference)
//
#include <hip/hip_runtime.h>

// Fused attention prefill, bf16 MFMA pipeline.
// ws layout (ushort units, 1M = 1024*1024):
//   xb 0..4M | wqkvb 4M..10M | wob 10M..14M | qkvb 14M..20M | qb 20M..24M
//   kb 24M..25M | vt 25M..26M | yb 26M..30M   => 60 MB total.

typedef __attribute__((ext_vector_type(8))) __bf16 bf16x8;
typedef __attribute__((ext_vector_type(4))) float f32x4;

#define S_LEN 2048
#define DIMN  2048
#define NH    32
#define NKV   8
#define HD    64
#define QKVF  3072

__device__ __forceinline__ ushort f2bf(float f) {
  union { float f; unsigned u; } v; v.f = f;
  unsigned r = v.u + 0x7fffu + ((v.u >> 16) & 1u);
  return (ushort)(r >> 16);
}
__device__ __forceinline__ unsigned pack_bf2_rz(float a, float b) {
  union { float f; unsigned u; } va, vb; va.f = a; vb.f = b;
  return (va.u >> 16) | (vb.u & 0xffff0000u);
}
__device__ __forceinline__ float bf2f(ushort u) {
  union { unsigned u; float f; } v; v.u = ((unsigned)u) << 16;
  return v.f;
}
__device__ __forceinline__ void gld_lds16(const void* g, void* l) {
  __builtin_amdgcn_global_load_lds(
      (const __attribute__((address_space(1))) unsigned int*)g,
      (__attribute__((address_space(3))) unsigned int*)l, 16, 0, 0);
}

// ---------------- f32 -> bf16 conversion (x, [wq;wk;wv], wo) ----------------
__global__ __launch_bounds__(256) void convert_all(
    const float* __restrict__ x, const float* __restrict__ wq,
    const float* __restrict__ wk, const float* __restrict__ wv,
    const float* __restrict__ wo, ushort* __restrict__ xb,
    ushort* __restrict__ wqkvb, ushort* __restrict__ wob) {
  const size_t NX = 4u * 1024 * 1024;
  const size_t NK = 1024 * 1024;
  size_t idx = ((size_t)blockIdx.x * 256 + threadIdx.x) * 4;
  const float* src; ushort* dst;
  if (idx < NX)                { src = x  + idx;                  dst = xb + idx; }
  else if (idx < 2 * NX)       { src = wq + (idx - NX);           dst = wqkvb + (idx - NX); }
  else if (idx < 2 * NX + NK)  { src = wk + (idx - 2 * NX);       dst = wqkvb + NX + (idx - 2 * NX); }
  else if (idx < 2 * NX + 2*NK){ src = wv + (idx - 2 * NX - NK);  dst = wqkvb + NX + NK + (idx - 2 * NX - NK); }
  else                         { src = wo + (idx - 2 * NX - 2*NK);dst = wob + (idx - 2 * NX - 2 * NK); }
  float4 v = *(const float4*)src;
  ushort4 o; o.x = f2bf(v.x); o.y = f2bf(v.y); o.z = f2bf(v.z); o.w = f2bf(v.w);
  *(ushort4*)dst = o;
}

// ---------------- GEMM: double-buffered LDS, prefetch-after-barrier ---------
// stage(k+1) issued right AFTER the barrier; compute(k) runs while loads fly;
// end-of-iteration barrier's vmcnt(0) drain is then nearly free. Critical at
// our 1-1.5 blocks/CU grids where no sibling block covers the drain.
template <int OUT_BF16>
__global__ __launch_bounds__(256) void gemm_bt(
    const ushort* __restrict__ A, const ushort* __restrict__ B,
    void* __restrict__ Cv, int M, int N, int K) {
  __shared__ __align__(16) ushort As[2][128 * 64];
  __shared__ __align__(16) ushort Bs[2][128 * 64];
  const int n0 = blockIdx.x * 128, m0 = blockIdx.y * 128;
  const int t = threadIdx.x;
  const int lane = t & 63, wave = t >> 6;
  const int wm = (wave >> 1) * 64, wn = (wave & 1) * 64;
  const int col = lane & 15, quad = lane >> 4;
  const int srow = wave * 32 + (lane >> 3);
  const int scol = (lane & 7) * 8;
  f32x4 acc[4][4] = {};

  auto stage = [&](int b, int kk) {
#pragma unroll
    for (int c = 0; c < 4; ++c) {
      int row = srow + c * 8;
      gld_lds16(&A[(size_t)(m0 + row) * K + kk + scol], &As[b][(wave * 32 + c * 8) * 64]);
      gld_lds16(&B[(size_t)(n0 + row) * K + kk + scol], &Bs[b][(wave * 32 + c * 8) * 64]);
    }
  };

  stage(0, 0);
  __syncthreads();
  for (int kk = 0; kk < K; kk += 64) {
    const int b = (kk >> 6) & 1;
    if (kk + 64 < K) stage(b ^ 1, kk + 64);
#pragma unroll
    for (int kc = 0; kc < 64; kc += 32) {
      bf16x8 af[4], bfr[4];
#pragma unroll
      for (int i = 0; i < 4; ++i)
        af[i] = *(const bf16x8*)&As[b][(wm + i * 16 + col) * 64 + kc + quad * 8];
#pragma unroll
      for (int j = 0; j < 4; ++j)
        bfr[j] = *(const bf16x8*)&Bs[b][(wn + j * 16 + col) * 64 + kc + quad * 8];
#pragma unroll
      for (int i = 0; i < 4; ++i)
#pragma unroll
        for (int j = 0; j < 4; ++j)
          acc[i][j] = __builtin_amdgcn_mfma_f32_16x16x32_bf16(af[i], bfr[j], acc[i][j], 0, 0, 0);
    }
    __syncthreads();
  }
#pragma unroll
  for (int i = 0; i < 4; ++i)
#pragma unroll
    for (int r = 0; r < 4; ++r) {
      int m = m0 + wm + i * 16 + quad * 4 + r;
      if (OUT_BF16) {
        ushort* C = (ushort*)Cv;
#pragma unroll
        for (int j = 0; j < 4; ++j)
          C[(size_t)m * N + n0 + wn + j * 16 + col] = f2bf(acc[i][j][r]);
      } else {
        float* C = (float*)Cv;
#pragma unroll
        for (int j = 0; j < 4; ++j)
          C[(size_t)m * N + n0 + wn + j * 16 + col] = acc[i][j][r];
      }
    }
}

// ---------------- RoPE + layout, coalesced ----------------------------------
// q pre-scaled by (1/8)*log2(e). vt stores keys permuted in each 64-tile:
// pos p holds key u=(p&3)*16+(p>>2) (matches attn P-store; PV invariant).
__global__ __launch_bounds__(256) void rope_layout(
    const ushort* __restrict__ qkv, const float* __restrict__ fc,
    const float* __restrict__ fs, ushort* __restrict__ qb,
    ushort* __restrict__ kb, ushort* __restrict__ vt) {
  __shared__ ushort T[64][72];
  const int hh = blockIdx.x;
  const int s0 = blockIdx.y * 256;
  const int t = threadIdx.x;
  if (hh < 40) {
    const int srcoff = (hh < 32) ? hh * 64 : 2048 + (hh - 32) * 64;
    ushort* dst = (hh < 32) ? qb + (size_t)hh * S_LEN * 64
                            : kb + (size_t)(hh - 32) * S_LEN * 64;
    const float qs = (hh < 32) ? 0.18033688011112042f : 1.0f;
    const int sr = t >> 4, dc = (t & 15) * 4, i0 = (t & 15) * 2;
#pragma unroll 4
    for (int pass = 0; pass < 16; ++pass) {
      int s = s0 + pass * 16 + sr;
      ushort4 vv = *(const ushort4*)&qkv[(size_t)s * QKVF + srcoff + dc];
      float2 cc = *(const float2*)&fc[s * 32 + i0];
      float2 ss = *(const float2*)&fs[s * 32 + i0];
      float xr0 = bf2f(vv.x), xi0 = bf2f(vv.y), xr1 = bf2f(vv.z), xi1 = bf2f(vv.w);
      ushort4 ov;
      ov.x = f2bf((xr0 * cc.x - xi0 * ss.x) * qs); ov.y = f2bf((xr0 * ss.x + xi0 * cc.x) * qs);
      ov.z = f2bf((xr1 * cc.y - xi1 * ss.y) * qs); ov.w = f2bf((xr1 * ss.y + xi1 * cc.y) * qs);
      *(ushort4*)&dst[(size_t)s * 64 + dc] = ov;
    }
  } else {
    const int vh = hh - 40;
    for (int sub = 0; sub < 4; ++sub) {
      int sb = s0 + sub * 64;
      int sr = t >> 2, dc = (t & 3) * 16;
      ushort tmp[16];
      *(int4*)&tmp[0] = *(const int4*)&qkv[(size_t)(sb + sr) * QKVF + 2560 + vh * 64 + dc];
      *(int4*)&tmp[8] = *(const int4*)&qkv[(size_t)(sb + sr) * QKVF + 2560 + vh * 64 + dc + 8];
      __syncthreads();
      const int pcol = ((sr & 15) << 2) | (sr >> 4);
#pragma unroll
      for (int k = 0; k < 16; ++k) T[dc + k][pcol] = tmp[k];
      __syncthreads();
      int d = t >> 2, sc2 = (t & 3) * 16;
      int4 w0 = *(const int4*)&T[d][sc2];
      int4 w1 = *(const int4*)&T[d][sc2 + 8];
      *(int4*)&vt[((size_t)vh * 64 + d) * S_LEN + sb + sc2] = w0;
      *(int4*)&vt[((size_t)vh * 64 + d) * S_LEN + sb + sc2 + 8] = w1;
    }
  }
}

// ---------------- Flash attention v6: paired strips + K-split + KV prefetch -
// Block (h,p): strips sA=63-p, sB=p (32 rows each), 33 tiles combined.
// 2 waves split the tile ranges; partial (O,l) merged via LDS (max-free
// softmax => additive). K AND V prefetched one full tile ahead.
struct KV8 { bf16x8 k[8]; bf16x8 v[8]; };

__global__ __launch_bounds__(128, 2) void attn(
    const ushort* __restrict__ qbg, const ushort* __restrict__ kbg,
    const ushort* __restrict__ vtg, ushort* __restrict__ yb) {
  __shared__ __align__(16) ushort Ps[2][2][2][16][72];  // [wave][parity][ss]
  __shared__ __align__(16) float MB[2][64][40];
  const int h = blockIdx.x;
  const int p = blockIdx.y;
  const int kvh = h >> 2;
  const int wave = threadIdx.x >> 6;
  const int lane = threadIdx.x & 63;
  const int col = lane & 15, quad = lane >> 4;
  const ushort* qh = qbg + (size_t)h * S_LEN * HD;
  const ushort* kh = kbg + (size_t)kvh * S_LEN * HD;
  const ushort* vh = vtg + (size_t)kvh * HD * S_LEN;

  const int sA = 63 - p, sB = p;
  const int ntA = (sA >> 1) + 1, ntB = (sB >> 1) + 1;
  const int ah = (ntA + 1) >> 1, bh = ntB >> 1;

  f32x4 o[2][4];
  f32x4 l[2];

  auto run_chunk = [&](int sX, int tb, int te) {
#pragma unroll
    for (int ss = 0; ss < 2; ++ss) {
      l[ss] = (f32x4){0.f, 0.f, 0.f, 0.f};
#pragma unroll
      for (int db = 0; db < 4; ++db) o[ss][db] = (f32x4){0.f, 0.f, 0.f, 0.f};
    }
    if (tb >= te) return;
    const int q0 = sX * 32;
    const int lastT = sX >> 1;
    bf16x8 qf[2][2];
#pragma unroll
    for (int ss = 0; ss < 2; ++ss)
#pragma unroll
      for (int c = 0; c < 2; ++c)
        qf[ss][c] = *(const bf16x8*)&qh[(size_t)(q0 + ss * 16 + col) * HD + c * 32 + quad * 8];
    KV8 b0, b1;
    auto loadKV = [&](int t0, KV8& kv) {
#pragma unroll
      for (int j = 0; j < 4; ++j)
#pragma unroll
        for (int c = 0; c < 2; ++c)
          kv.k[j * 2 + c] = *(const bf16x8*)&kh[(size_t)(t0 + j * 16 + col) * HD + c * 32 + quad * 8];
#pragma unroll
      for (int db = 0; db < 4; ++db)
#pragma unroll
        for (int c = 0; c < 2; ++c)
          kv.v[db * 2 + c] = *(const bf16x8*)&vh[(size_t)(db * 16 + col) * S_LEN + t0 + c * 32 + quad * 8];
    };
    auto body = [&](int it, KV8& cur, KV8& nxt) {
      const int t0 = it * 64;
      const int pb = it & 1;
      f32x4 sc[2][4] = {};
#pragma unroll
      for (int j = 0; j < 4; ++j)
#pragma unroll
        for (int ss = 0; ss < 2; ++ss) {
          sc[ss][j] = __builtin_amdgcn_mfma_f32_16x16x32_bf16(qf[ss][0], cur.k[j * 2], sc[ss][j], 0, 0, 0);
          sc[ss][j] = __builtin_amdgcn_mfma_f32_16x16x32_bf16(qf[ss][1], cur.k[j * 2 + 1], sc[ss][j], 0, 0, 0);
        }
      if (it + 1 < te) loadKV(t0 + 64, nxt);
      const bool masked = (it == lastT);
#pragma unroll
      for (int ss = 0; ss < 2; ++ss)
#pragma unroll
        for (int r = 0; r < 4; ++r) {
          const int rowq = q0 + ss * 16 + quad * 4 + r;
          float pr[4];
#pragma unroll
          for (int j = 0; j < 4; ++j) {
            float e = __builtin_amdgcn_exp2f(sc[ss][j][r]);
            if (masked) e = (t0 + j * 16 + col > rowq) ? 0.f : e;
            pr[j] = e;
          }
          l[ss][r] += (pr[0] + pr[1]) + (pr[2] + pr[3]);
          uint2 pk;
          pk.x = pack_bf2_rz(pr[0], pr[1]);
          pk.y = pack_bf2_rz(pr[2], pr[3]);
          *(uint2*)&Ps[wave][pb][ss][quad * 4 + r][col * 4] = pk;
        }
#pragma unroll
      for (int c = 0; c < 2; ++c)
#pragma unroll
        for (int ss = 0; ss < 2; ++ss) {
          bf16x8 pf = *(const bf16x8*)&Ps[wave][pb][ss][col][c * 32 + quad * 8];
#pragma unroll
          for (int db = 0; db < 4; ++db)
            o[ss][db] = __builtin_amdgcn_mfma_f32_16x16x32_bf16(pf, cur.v[db * 2 + c], o[ss][db], 0, 0, 0);
        }
    };
    loadKV(tb * 64, b0);
    int it = tb;
    while (true) {
      body(it, b0, b1);
      if (++it == te) break;
      body(it, b1, b0);
      if (++it == te) break;
    }
  };

  auto dump = [&](int strip) {
#pragma unroll
    for (int ss = 0; ss < 2; ++ss) {
#pragma unroll
      for (int db = 0; db < 4; ++db)
        *(f32x4*)&MB[strip][lane][ss * 16 + db * 4] = o[ss][db];
      *(f32x4*)&MB[strip][lane][32 + ss * 4] = l[ss];
    }
  };
  auto merge = [&](int strip) {
#pragma unroll
    for (int ss = 0; ss < 2; ++ss) {
#pragma unroll
      for (int db = 0; db < 4; ++db)
        o[ss][db] += *(const f32x4*)&MB[strip][lane][ss * 16 + db * 4];
      l[ss] += *(const f32x4*)&MB[strip][lane][32 + ss * 4];
    }
  };

  const int s1 = wave ? sA : sB;
  const int t1b = wave ? ah : 0, t1e = wave ? ntA : bh;
  const int s2 = wave ? sB : sA;
  const int t2b = wave ? bh : 0, t2e = wave ? ntB : ah;
  const int dumpIdx = wave ? 0 : 1;

  run_chunk(s1, t1b, t1e);
  dump(dumpIdx);
  run_chunk(s2, t2b, t2e);
  __syncthreads();
  merge(dumpIdx ^ 1);

  const int q0 = s2 * 32;
#pragma unroll
  for (int ss = 0; ss < 2; ++ss)
#pragma unroll
    for (int r = 0; r < 4; ++r) {
      float ls = l[ss][r];
      ls += __shfl_xor(ls, 1);
      ls += __shfl_xor(ls, 2);
      ls += __shfl_xor(ls, 4);
      ls += __shfl_xor(ls, 8);
      float inv = 1.0f / ls;
      int rowq = q0 + ss * 16 + quad * 4 + r;
#pragma unroll
      for (int db = 0; db < 4; ++db)
        yb[(size_t)rowq * (NH * HD) + h * HD + db * 16 + col] = f2bf(o[ss][db][r] * inv);
    }
}

extern "C" void kernel_launch(void* const* d_in, const int* in_sizes, int n_in,
                              void* d_out, int out_size, void* d_ws, size_t ws_size,
                              hipStream_t stream) {
  (void)in_sizes; (void)n_in; (void)out_size; (void)ws_size;
  const float* x  = (const float*)d_in[0];
  const float* fc = (const float*)d_in[1];
  const float* fs = (const float*)d_in[2];
  const float* wq = (const float*)d_in[4];
  const float* wk = (const float*)d_in[5];
  const float* wv = (const float*)d_in[6];
  const float* wo = (const float*)d_in[7];
  ushort* w = (ushort*)d_ws;
  const size_t M1 = 1024 * 1024;
  ushort* xb    = w;
  ushort* wqkvb = w + 4 * M1;
  ushort* wob   = w + 10 * M1;
  ushort* qkvb  = w + 14 * M1;
  ushort* qb    = w + 20 * M1;
  ushort* kb    = w + 24 * M1;
  ushort* vt    = w + 25 * M1;
  ushort* yb    = w + 26 * M1;

  convert_all<<<14336, 256, 0, stream>>>(x, wq, wk, wv, wo, xb, wqkvb, wob);
  gemm_bt<1><<<dim3(QKVF / 128, S_LEN / 128), 256, 0, stream>>>(xb, wqkvb, qkvb, S_LEN, QKVF, DIMN);
  rope_layout<<<dim3(48, 8), 256, 0, stream>>>(qkvb, fc, fs, qb, kb, vt);
  attn<<<dim3(NH, 32), 128, 0, stream>>>(qb, kb, vt, yb);
  gemm_bt<0><<<dim3(DIMN / 128, S_LEN / 128), 256, 0, stream>>>(yb, wob, d_out, S_LEN, DIMN, NH * HD);
}

// Round 7
// 253.795 us; speedup vs baseline: 1.1664x; 1.1664x over previous
//
#include <hip/hip_runtime.h>

// Fused attention prefill, bf16 MFMA pipeline.
// ws layout (ushort units, 1M = 1024*1024):
//   xb 0..4M | wqkvb 4M..10M | wob 10M..14M | qkvb 14M..20M | qb 20M..24M
//   kb 24M..25M | vt 25M..26M | yb 26M..30M   => 60 MB total.
// kb/vt layout: [kvh][tile(32)][512 chunks][8 ushort]; chunk (r,ch) of the
// 64x64 tile lives at linear pos r*8 + (ch ^ (r&7))  (bank-swizzle so that
// ds_read_b128 of column-chunk ch over rows r is 2-way max = free).
// kb rows r = keys (natural); vt rows r = dims, columns = sigma-permuted key
// positions: pos p holds key u=(p&3)*16+(p>>2), matching attn's P store.

typedef __attribute__((ext_vector_type(8))) __bf16 bf16x8;
typedef __attribute__((ext_vector_type(4))) float f32x4;

#define S_LEN 2048
#define DIMN  2048
#define NH    32
#define NKV   8
#define HD    64
#define QKVF  3072

__device__ __forceinline__ ushort f2bf(float f) {
  union { float f; unsigned u; } v; v.f = f;
  unsigned r = v.u + 0x7fffu + ((v.u >> 16) & 1u);
  return (ushort)(r >> 16);
}
__device__ __forceinline__ unsigned pack_bf2_rz(float a, float b) {
  union { float f; unsigned u; } va, vb; va.f = a; vb.f = b;
  return (va.u >> 16) | (vb.u & 0xffff0000u);
}
__device__ __forceinline__ float bf2f(ushort u) {
  union { unsigned u; float f; } v; v.u = ((unsigned)u) << 16;
  return v.f;
}
__device__ __forceinline__ void gld_lds16(const void* g, void* l) {
  __builtin_amdgcn_global_load_lds(
      (const __attribute__((address_space(1))) unsigned int*)g,
      (__attribute__((address_space(3))) unsigned int*)l, 16, 0, 0);
}

// ---------------- f32 -> bf16 conversion (x, [wq;wk;wv], wo) ----------------
__global__ __launch_bounds__(256) void convert_all(
    const float* __restrict__ x, const float* __restrict__ wq,
    const float* __restrict__ wk, const float* __restrict__ wv,
    const float* __restrict__ wo, ushort* __restrict__ xb,
    ushort* __restrict__ wqkvb, ushort* __restrict__ wob) {
  const size_t NX = 4u * 1024 * 1024;
  const size_t NK = 1024 * 1024;
  size_t idx = ((size_t)blockIdx.x * 256 + threadIdx.x) * 4;
  const float* src; ushort* dst;
  if (idx < NX)                { src = x  + idx;                  dst = xb + idx; }
  else if (idx < 2 * NX)       { src = wq + (idx - NX);           dst = wqkvb + (idx - NX); }
  else if (idx < 2 * NX + NK)  { src = wk + (idx - 2 * NX);       dst = wqkvb + NX + (idx - 2 * NX); }
  else if (idx < 2 * NX + 2*NK){ src = wv + (idx - 2 * NX - NK);  dst = wqkvb + NX + NK + (idx - 2 * NX - NK); }
  else                         { src = wo + (idx - 2 * NX - 2*NK);dst = wob + (idx - 2 * NX - 2 * NK); }
  float4 v = *(const float4*)src;
  ushort4 o; o.x = f2bf(v.x); o.y = f2bf(v.y); o.z = f2bf(v.z); o.w = f2bf(v.w);
  *(ushort4*)dst = o;
}

// ---------------- GEMM: double-buffered LDS, global_load_lds width-16 -------
template <int OUT_BF16>
__global__ __launch_bounds__(256) void gemm_bt(
    const ushort* __restrict__ A, const ushort* __restrict__ B,
    void* __restrict__ Cv, int M, int N, int K) {
  __shared__ __align__(16) ushort As[2][128 * 64];
  __shared__ __align__(16) ushort Bs[2][128 * 64];
  const int n0 = blockIdx.x * 128, m0 = blockIdx.y * 128;
  const int t = threadIdx.x;
  const int lane = t & 63, wave = t >> 6;
  const int wm = (wave >> 1) * 64, wn = (wave & 1) * 64;
  const int col = lane & 15, quad = lane >> 4;
  const int srow = wave * 32 + (lane >> 3);
  const int scol = (lane & 7) * 8;
  f32x4 acc[4][4] = {};

  auto stage = [&](int b, int kk) {
#pragma unroll
    for (int c = 0; c < 4; ++c) {
      int row = srow + c * 8;
      gld_lds16(&A[(size_t)(m0 + row) * K + kk + scol], &As[b][(wave * 32 + c * 8) * 64]);
      gld_lds16(&B[(size_t)(n0 + row) * K + kk + scol], &Bs[b][(wave * 32 + c * 8) * 64]);
    }
  };

  stage(0, 0);
  __syncthreads();
  for (int kk = 0; kk < K; kk += 64) {
    const int b = (kk >> 6) & 1;
    if (kk + 64 < K) stage(b ^ 1, kk + 64);
#pragma unroll
    for (int kc = 0; kc < 64; kc += 32) {
      bf16x8 af[4], bfr[4];
#pragma unroll
      for (int i = 0; i < 4; ++i)
        af[i] = *(const bf16x8*)&As[b][(wm + i * 16 + col) * 64 + kc + quad * 8];
#pragma unroll
      for (int j = 0; j < 4; ++j)
        bfr[j] = *(const bf16x8*)&Bs[b][(wn + j * 16 + col) * 64 + kc + quad * 8];
#pragma unroll
      for (int i = 0; i < 4; ++i)
#pragma unroll
        for (int j = 0; j < 4; ++j)
          acc[i][j] = __builtin_amdgcn_mfma_f32_16x16x32_bf16(af[i], bfr[j], acc[i][j], 0, 0, 0);
    }
    __syncthreads();
  }
#pragma unroll
  for (int i = 0; i < 4; ++i)
#pragma unroll
    for (int r = 0; r < 4; ++r) {
      int m = m0 + wm + i * 16 + quad * 4 + r;
      if (OUT_BF16) {
        ushort* C = (ushort*)Cv;
#pragma unroll
        for (int j = 0; j < 4; ++j)
          C[(size_t)m * N + n0 + wn + j * 16 + col] = f2bf(acc[i][j][r]);
      } else {
        float* C = (float*)Cv;
#pragma unroll
        for (int j = 0; j < 4; ++j)
          C[(size_t)m * N + n0 + wn + j * 16 + col] = acc[i][j][r];
      }
    }
}

// ---------------- RoPE + layout ---------------------------------------------
// q (hh<32): natural [h][s][64], pre-scaled by (1/8)*log2(e).
// k (32<=hh<40): swizzled tile layout (see header comment).
// v (hh>=40): LDS transpose -> [d][sigma-permuted pos], swizzled tile layout.
__global__ __launch_bounds__(256) void rope_layout(
    const ushort* __restrict__ qkv, const float* __restrict__ fc,
    const float* __restrict__ fs, ushort* __restrict__ qb,
    ushort* __restrict__ kb, ushort* __restrict__ vt) {
  __shared__ ushort T[64][72];
  const int hh = blockIdx.x;
  const int s0 = blockIdx.y * 256;
  const int t = threadIdx.x;
  if (hh < 32) {
    ushort* dst = qb + (size_t)hh * S_LEN * 64;
    const float qs = 0.18033688011112042f;  // (1/8)*log2(e)
    const int sr = t >> 4, dc = (t & 15) * 4, i0 = (t & 15) * 2;
#pragma unroll 4
    for (int pass = 0; pass < 16; ++pass) {
      int s = s0 + pass * 16 + sr;
      ushort4 vv = *(const ushort4*)&qkv[(size_t)s * QKVF + hh * 64 + dc];
      float2 cc = *(const float2*)&fc[s * 32 + i0];
      float2 ss = *(const float2*)&fs[s * 32 + i0];
      float xr0 = bf2f(vv.x), xi0 = bf2f(vv.y), xr1 = bf2f(vv.z), xi1 = bf2f(vv.w);
      ushort4 ov;
      ov.x = f2bf((xr0 * cc.x - xi0 * ss.x) * qs); ov.y = f2bf((xr0 * ss.x + xi0 * cc.x) * qs);
      ov.z = f2bf((xr1 * cc.y - xi1 * ss.y) * qs); ov.w = f2bf((xr1 * ss.y + xi1 * cc.y) * qs);
      *(ushort4*)&dst[(size_t)s * 64 + dc] = ov;
    }
  } else if (hh < 40) {
    const int kh2 = hh - 32;
    const int sr8 = t >> 3;     // row within 32-row pass
    const int ch = t & 7;       // 8-dim chunk
#pragma unroll 2
    for (int pass = 0; pass < 8; ++pass) {
      int s = s0 + pass * 32 + sr8;
      ushort in[8], out[8];
      *(int4*)&in[0] = *(const int4*)&qkv[(size_t)s * QKVF + 2048 + kh2 * 64 + ch * 8];
      float4 cc = *(const float4*)&fc[s * 32 + ch * 4];
      float4 ss4 = *(const float4*)&fs[s * 32 + ch * 4];
      const float* cp = &cc.x; const float* sp = &ss4.x;
#pragma unroll
      for (int i = 0; i < 4; ++i) {
        float xr = bf2f(in[2 * i]), xi = bf2f(in[2 * i + 1]);
        out[2 * i]     = f2bf(xr * cp[i] - xi * sp[i]);
        out[2 * i + 1] = f2bf(xr * sp[i] + xi * cp[i]);
      }
      int r = s & 63, tile = s >> 6;
      size_t pos = ((size_t)(kh2 * 32 + tile)) * 4096 + (r * 8 + (ch ^ (r & 7))) * 8;
      *(int4*)&kb[pos] = *(const int4*)&out[0];
    }
  } else {
    const int vh = hh - 40;
    for (int sub = 0; sub < 4; ++sub) {
      int sb = s0 + sub * 64;
      int sr = t >> 2, dc = (t & 3) * 16;
      ushort tmp[16];
      *(int4*)&tmp[0] = *(const int4*)&qkv[(size_t)(sb + sr) * QKVF + 2560 + vh * 64 + dc];
      *(int4*)&tmp[8] = *(const int4*)&qkv[(size_t)(sb + sr) * QKVF + 2560 + vh * 64 + dc + 8];
      __syncthreads();
      const int pcol = ((sr & 15) << 2) | (sr >> 4);  // sigma: key sr -> position
#pragma unroll
      for (int k = 0; k < 16; ++k) T[dc + k][pcol] = tmp[k];
      __syncthreads();
      int d = t >> 2;
      int ch0 = (t & 3) * 2, ch1 = ch0 + 1;
      int tile = sb >> 6;
      size_t base = ((size_t)(vh * 32 + tile)) * 4096;
      *(int4*)&vt[base + (d * 8 + (ch0 ^ (d & 7))) * 8] = *(const int4*)&T[d][ch0 * 8];
      *(int4*)&vt[base + (d * 8 + (ch1 ^ (d & 7))) * 8] = *(const int4*)&T[d][ch1 * 8];
    }
  }
}

// ---------------- Flash attention v7: LDS-shared KV, 4 GQA heads per block --
// Block (kvh, p): 4 waves = 4 q-heads sharing kvh. Strips 127-p then p (16
// rows): 33-34 tiles/block, perfectly balanced. K+V tiles staged into LDS
// double-buffer via global_load_lds one tile ahead; one barrier per tile.
__global__ __launch_bounds__(256, 2) void attn(
    const ushort* __restrict__ qbg, const ushort* __restrict__ kbg,
    const ushort* __restrict__ vtg, ushort* __restrict__ yb) {
  __shared__ __align__(16) ushort Ks[2][4096];
  __shared__ __align__(16) ushort Vs[2][4096];
  __shared__ __align__(16) ushort Ps[4][2][16][72];
  const int kvh = blockIdx.x;
  const int p = blockIdx.y;
  const int wave = threadIdx.x >> 6;
  const int lane = threadIdx.x & 63;
  const int col = lane & 15, quad = lane >> 4;
  const int h = kvh * 4 + wave;
  const ushort* qh = qbg + (size_t)h * S_LEN * HD;
  const ushort* kbase = kbg + (size_t)kvh * 32 * 4096;
  const ushort* vbase = vtg + (size_t)kvh * 32 * 4096;
  const int rsw = col & 7;  // bank-swizzle key

  auto stage = [&](int tile, int buf) {
#pragma unroll
    for (int g = 0; g < 2; ++g) {
      int gg = wave + g * 4;
      gld_lds16(kbase + (size_t)tile * 4096 + gg * 512 + lane * 8, &Ks[buf][gg * 512]);
      gld_lds16(vbase + (size_t)tile * 4096 + gg * 512 + lane * 8, &Vs[buf][gg * 512]);
    }
  };

  auto do_strip = [&](int s) {
    const int nt = (s >> 2) + 1;
    const int q0 = s * 16;
    bf16x8 qf[2];
    qf[0] = *(const bf16x8*)&qh[(size_t)(q0 + col) * HD + quad * 8];
    qf[1] = *(const bf16x8*)&qh[(size_t)(q0 + col) * HD + 32 + quad * 8];
    float l[4] = {};
    f32x4 o[4] = {};
    stage(0, 0);
    __syncthreads();
    for (int t = 0; t < nt; ++t) {
      const int buf = t & 1;
      if (t + 1 < nt) stage(t + 1, buf ^ 1);
      // QK^T: B-frags from swizzled LDS K tile
      f32x4 sc[4] = {};
#pragma unroll
      for (int c = 0; c < 2; ++c) {
        const int chs = (c * 4 + quad) ^ rsw;
#pragma unroll
        for (int j = 0; j < 4; ++j) {
          bf16x8 kf = *(const bf16x8*)&Ks[buf][((j * 16 + col) * 8 + chs) * 8];
          sc[j] = __builtin_amdgcn_mfma_f32_16x16x32_bf16(qf[c], kf, sc[j], 0, 0, 0);
        }
      }
      const bool masked = (t == nt - 1);
#pragma unroll
      for (int r = 0; r < 4; ++r) {
        const int rowq = q0 + quad * 4 + r;
        float pr[4];
#pragma unroll
        for (int j = 0; j < 4; ++j) {
          float e = __builtin_amdgcn_exp2f(sc[j][r]);
          if (masked) e = (t * 64 + j * 16 + col > rowq) ? 0.f : e;
          pr[j] = e;
        }
        l[r] += (pr[0] + pr[1]) + (pr[2] + pr[3]);
        uint2 pk;
        pk.x = pack_bf2_rz(pr[0], pr[1]);
        pk.y = pack_bf2_rz(pr[2], pr[3]);
        *(uint2*)&Ps[wave][buf][quad * 4 + r][col * 4] = pk;
      }
      // PV: A-frag = P from LDS, B-frags = V from swizzled LDS V tile
#pragma unroll
      for (int c = 0; c < 2; ++c) {
        const int chs = (c * 4 + quad) ^ rsw;
        bf16x8 pf = *(const bf16x8*)&Ps[wave][buf][col][c * 32 + quad * 8];
#pragma unroll
        for (int db = 0; db < 4; ++db) {
          bf16x8 vf = *(const bf16x8*)&Vs[buf][((db * 16 + col) * 8 + chs) * 8];
          o[db] = __builtin_amdgcn_mfma_f32_16x16x32_bf16(pf, vf, o[db], 0, 0, 0);
        }
      }
      __syncthreads();
    }
#pragma unroll
    for (int r = 0; r < 4; ++r) {
      float ls = l[r];
      ls += __shfl_xor(ls, 1);
      ls += __shfl_xor(ls, 2);
      ls += __shfl_xor(ls, 4);
      ls += __shfl_xor(ls, 8);
      float inv = 1.0f / ls;
      int rowq = q0 + quad * 4 + r;
#pragma unroll
      for (int db = 0; db < 4; ++db)
        yb[(size_t)rowq * (NH * HD) + h * HD + db * 16 + col] = f2bf(o[db][r] * inv);
    }
  };

  do_strip(127 - p);
  do_strip(p);
}

extern "C" void kernel_launch(void* const* d_in, const int* in_sizes, int n_in,
                              void* d_out, int out_size, void* d_ws, size_t ws_size,
                              hipStream_t stream) {
  (void)in_sizes; (void)n_in; (void)out_size; (void)ws_size;
  const float* x  = (const float*)d_in[0];
  const float* fc = (const float*)d_in[1];
  const float* fs = (const float*)d_in[2];
  const float* wq = (const float*)d_in[4];
  const float* wk = (const float*)d_in[5];
  const float* wv = (const float*)d_in[6];
  const float* wo = (const float*)d_in[7];
  ushort* w = (ushort*)d_ws;
  const size_t M1 = 1024 * 1024;
  ushort* xb    = w;
  ushort* wqkvb = w + 4 * M1;
  ushort* wob   = w + 10 * M1;
  ushort* qkvb  = w + 14 * M1;
  ushort* qb    = w + 20 * M1;
  ushort* kb    = w + 24 * M1;
  ushort* vt    = w + 25 * M1;
  ushort* yb    = w + 26 * M1;

  convert_all<<<14336, 256, 0, stream>>>(x, wq, wk, wv, wo, xb, wqkvb, wob);
  gemm_bt<1><<<dim3(QKVF / 128, S_LEN / 128), 256, 0, stream>>>(xb, wqkvb, qkvb, S_LEN, QKVF, DIMN);
  rope_layout<<<dim3(48, 8), 256, 0, stream>>>(qkvb, fc, fs, qb, kb, vt);
  attn<<<dim3(NKV, 64), 256, 0, stream>>>(qb, kb, vt, yb);
  gemm_bt<0><<<dim3(DIMN / 128, S_LEN / 128), 256, 0, stream>>>(yb, wob, d_out, S_LEN, DIMN, NH * HD);
}

// Round 8
// 233.344 us; speedup vs baseline: 1.2686x; 1.0876x over previous
//
#include <hip/hip_runtime.h>

// Fused attention prefill, bf16 MFMA pipeline.
// ws layout (ushort units, 1M = 1024*1024):
//   xb 0..4M | wqkvb 4M..10M | wob 10M..14M | qkvb 14M..20M | qb 20M..24M
//   kb 24M..25M | vt 25M..26M | yb 26M..30M   => 60 MB total.
// kb/vt layout: [kvh][tile(32)][512 chunks][8 ushort]; chunk (r,ch) of the
// 64x64 tile lives at linear pos r*8 + (ch ^ (r&7))  (bank-swizzle so that
// ds_read_b128 of column-chunk ch over rows r is spread over all banks).
// kb rows r = keys (natural); vt rows r = dims, columns = sigma-permuted key
// positions: pos p holds key u=(p&3)*16+(p>>2), matching attn's P store.

typedef __attribute__((ext_vector_type(8))) __bf16 bf16x8;
typedef __attribute__((ext_vector_type(4))) float f32x4;

#define S_LEN 2048
#define DIMN  2048
#define NH    32
#define NKV   8
#define HD    64
#define QKVF  3072

__device__ __forceinline__ ushort f2bf(float f) {
  union { float f; unsigned u; } v; v.f = f;
  unsigned r = v.u + 0x7fffu + ((v.u >> 16) & 1u);
  return (ushort)(r >> 16);
}
__device__ __forceinline__ unsigned pack_bf2_rz(float a, float b) {
  union { float f; unsigned u; } va, vb; va.f = a; vb.f = b;
  return (va.u >> 16) | (vb.u & 0xffff0000u);
}
__device__ __forceinline__ float bf2f(ushort u) {
  union { unsigned u; float f; } v; v.u = ((unsigned)u) << 16;
  return v.f;
}
__device__ __forceinline__ void gld_lds16(const void* g, void* l) {
  __builtin_amdgcn_global_load_lds(
      (const __attribute__((address_space(1))) unsigned int*)g,
      (__attribute__((address_space(3))) unsigned int*)l, 16, 0, 0);
}

// ---------------- f32 -> bf16 conversion (x, [wq;wk;wv], wo) ----------------
__global__ __launch_bounds__(256) void convert_all(
    const float* __restrict__ x, const float* __restrict__ wq,
    const float* __restrict__ wk, const float* __restrict__ wv,
    const float* __restrict__ wo, ushort* __restrict__ xb,
    ushort* __restrict__ wqkvb, ushort* __restrict__ wob) {
  const size_t NX = 4u * 1024 * 1024;
  const size_t NK = 1024 * 1024;
  size_t idx = ((size_t)blockIdx.x * 256 + threadIdx.x) * 4;
  const float* src; ushort* dst;
  if (idx < NX)                { src = x  + idx;                  dst = xb + idx; }
  else if (idx < 2 * NX)       { src = wq + (idx - NX);           dst = wqkvb + (idx - NX); }
  else if (idx < 2 * NX + NK)  { src = wk + (idx - 2 * NX);       dst = wqkvb + NX + (idx - 2 * NX); }
  else if (idx < 2 * NX + 2*NK){ src = wv + (idx - 2 * NX - NK);  dst = wqkvb + NX + NK + (idx - 2 * NX - NK); }
  else                         { src = wo + (idx - 2 * NX - 2*NK);dst = wob + (idx - 2 * NX - 2 * NK); }
  float4 v = *(const float4*)src;
  ushort4 o; o.x = f2bf(v.x); o.y = f2bf(v.y); o.z = f2bf(v.z); o.w = f2bf(v.w);
  *(ushort4*)dst = o;
}

// ---------------- GEMM: dbuf LDS + XOR bank swizzle -------------------------
// LDS tile is unpadded (global_load_lds), so chunk (row,ch) is stored at
// physical position ch^(row&7): staging permutes the GLOBAL source chunk per
// lane (same 128B window per 8-lane row group -> coalescing unchanged);
// fragment reads use chunk=(c*4+quad)^(col&7). Spreads each ds_read_b128
// over all 8 chunk positions -> 8 accesses/bank = minimum (was 16 = 2x stall,
// 9.4M SQ_LDS_BANK_CONFLICT in R7).
template <int OUT_BF16>
__global__ __launch_bounds__(256) void gemm_bt(
    const ushort* __restrict__ A, const ushort* __restrict__ B,
    void* __restrict__ Cv, int M, int N, int K) {
  __shared__ __align__(16) ushort As[2][128 * 64];
  __shared__ __align__(16) ushort Bs[2][128 * 64];
  const int n0 = blockIdx.x * 128, m0 = blockIdx.y * 128;
  const int t = threadIdx.x;
  const int lane = t & 63, wave = t >> 6;
  const int wm = (wave >> 1) * 64, wn = (wave & 1) * 64;
  const int col = lane & 15, quad = lane >> 4;
  const int sw = col & 7;                     // fragment-read swizzle key
  const int srow = wave * 32 + (lane >> 3);
  const int scol = ((lane & 7) ^ (lane >> 3)) * 8;  // staged-source swizzle
  f32x4 acc[4][4] = {};

  auto stage = [&](int b, int kk) {
#pragma unroll
    for (int c = 0; c < 4; ++c) {
      int row = srow + c * 8;
      gld_lds16(&A[(size_t)(m0 + row) * K + kk + scol], &As[b][(wave * 32 + c * 8) * 64]);
      gld_lds16(&B[(size_t)(n0 + row) * K + kk + scol], &Bs[b][(wave * 32 + c * 8) * 64]);
    }
  };

  stage(0, 0);
  __syncthreads();
  for (int kk = 0; kk < K; kk += 64) {
    const int b = (kk >> 6) & 1;
    if (kk + 64 < K) stage(b ^ 1, kk + 64);
#pragma unroll
    for (int c = 0; c < 2; ++c) {
      const int chs = ((c * 4 + quad) ^ sw) * 8;
      bf16x8 af[4], bfr[4];
#pragma unroll
      for (int i = 0; i < 4; ++i)
        af[i] = *(const bf16x8*)&As[b][(wm + i * 16 + col) * 64 + chs];
#pragma unroll
      for (int j = 0; j < 4; ++j)
        bfr[j] = *(const bf16x8*)&Bs[b][(wn + j * 16 + col) * 64 + chs];
#pragma unroll
      for (int i = 0; i < 4; ++i)
#pragma unroll
        for (int j = 0; j < 4; ++j)
          acc[i][j] = __builtin_amdgcn_mfma_f32_16x16x32_bf16(af[i], bfr[j], acc[i][j], 0, 0, 0);
    }
    __syncthreads();
  }
#pragma unroll
  for (int i = 0; i < 4; ++i)
#pragma unroll
    for (int r = 0; r < 4; ++r) {
      int m = m0 + wm + i * 16 + quad * 4 + r;
      if (OUT_BF16) {
        ushort* C = (ushort*)Cv;
#pragma unroll
        for (int j = 0; j < 4; ++j)
          C[(size_t)m * N + n0 + wn + j * 16 + col] = f2bf(acc[i][j][r]);
      } else {
        float* C = (float*)Cv;
#pragma unroll
        for (int j = 0; j < 4; ++j)
          C[(size_t)m * N + n0 + wn + j * 16 + col] = acc[i][j][r];
      }
    }
}

// ---------------- RoPE + layout ---------------------------------------------
// q (hh<32): natural [h][s][64], pre-scaled by (1/8)*log2(e).
// k (32<=hh<40): swizzled tile layout (see header comment).
// v (hh>=40): LDS transpose -> [d][sigma-permuted pos], swizzled tile layout.
__global__ __launch_bounds__(256) void rope_layout(
    const ushort* __restrict__ qkv, const float* __restrict__ fc,
    const float* __restrict__ fs, ushort* __restrict__ qb,
    ushort* __restrict__ kb, ushort* __restrict__ vt) {
  __shared__ ushort T[64][72];
  const int hh = blockIdx.x;
  const int s0 = blockIdx.y * 256;
  const int t = threadIdx.x;
  if (hh < 32) {
    ushort* dst = qb + (size_t)hh * S_LEN * 64;
    const float qs = 0.18033688011112042f;  // (1/8)*log2(e)
    const int sr = t >> 4, dc = (t & 15) * 4, i0 = (t & 15) * 2;
#pragma unroll 4
    for (int pass = 0; pass < 16; ++pass) {
      int s = s0 + pass * 16 + sr;
      ushort4 vv = *(const ushort4*)&qkv[(size_t)s * QKVF + hh * 64 + dc];
      float2 cc = *(const float2*)&fc[s * 32 + i0];
      float2 ss = *(const float2*)&fs[s * 32 + i0];
      float xr0 = bf2f(vv.x), xi0 = bf2f(vv.y), xr1 = bf2f(vv.z), xi1 = bf2f(vv.w);
      ushort4 ov;
      ov.x = f2bf((xr0 * cc.x - xi0 * ss.x) * qs); ov.y = f2bf((xr0 * ss.x + xi0 * cc.x) * qs);
      ov.z = f2bf((xr1 * cc.y - xi1 * ss.y) * qs); ov.w = f2bf((xr1 * ss.y + xi1 * cc.y) * qs);
      *(ushort4*)&dst[(size_t)s * 64 + dc] = ov;
    }
  } else if (hh < 40) {
    const int kh2 = hh - 32;
    const int sr8 = t >> 3;     // row within 32-row pass
    const int ch = t & 7;       // 8-dim chunk
#pragma unroll 2
    for (int pass = 0; pass < 8; ++pass) {
      int s = s0 + pass * 32 + sr8;
      ushort in[8], out[8];
      *(int4*)&in[0] = *(const int4*)&qkv[(size_t)s * QKVF + 2048 + kh2 * 64 + ch * 8];
      float4 cc = *(const float4*)&fc[s * 32 + ch * 4];
      float4 ss4 = *(const float4*)&fs[s * 32 + ch * 4];
      const float* cp = &cc.x; const float* sp = &ss4.x;
#pragma unroll
      for (int i = 0; i < 4; ++i) {
        float xr = bf2f(in[2 * i]), xi = bf2f(in[2 * i + 1]);
        out[2 * i]     = f2bf(xr * cp[i] - xi * sp[i]);
        out[2 * i + 1] = f2bf(xr * sp[i] + xi * cp[i]);
      }
      int r = s & 63, tile = s >> 6;
      size_t pos = ((size_t)(kh2 * 32 + tile)) * 4096 + (r * 8 + (ch ^ (r & 7))) * 8;
      *(int4*)&kb[pos] = *(const int4*)&out[0];
    }
  } else {
    const int vh = hh - 40;
    for (int sub = 0; sub < 4; ++sub) {
      int sb = s0 + sub * 64;
      int sr = t >> 2, dc = (t & 3) * 16;
      ushort tmp[16];
      *(int4*)&tmp[0] = *(const int4*)&qkv[(size_t)(sb + sr) * QKVF + 2560 + vh * 64 + dc];
      *(int4*)&tmp[8] = *(const int4*)&qkv[(size_t)(sb + sr) * QKVF + 2560 + vh * 64 + dc + 8];
      __syncthreads();
      const int pcol = ((sr & 15) << 2) | (sr >> 4);  // sigma: key sr -> position
#pragma unroll
      for (int k = 0; k < 16; ++k) T[dc + k][pcol] = tmp[k];
      __syncthreads();
      int d = t >> 2;
      int ch0 = (t & 3) * 2, ch1 = ch0 + 1;
      int tile = sb >> 6;
      size_t base = ((size_t)(vh * 32 + tile)) * 4096;
      *(int4*)&vt[base + (d * 8 + (ch0 ^ (d & 7))) * 8] = *(const int4*)&T[d][ch0 * 8];
      *(int4*)&vt[base + (d * 8 + (ch1 ^ (d & 7))) * 8] = *(const int4*)&T[d][ch1 * 8];
    }
  }
}

// ---------------- Flash attention v7: LDS-shared KV, 4 GQA heads per block --
__global__ __launch_bounds__(256, 2) void attn(
    const ushort* __restrict__ qbg, const ushort* __restrict__ kbg,
    const ushort* __restrict__ vtg, ushort* __restrict__ yb) {
  __shared__ __align__(16) ushort Ks[2][4096];
  __shared__ __align__(16) ushort Vs[2][4096];
  __shared__ __align__(16) ushort Ps[4][2][16][72];
  const int kvh = blockIdx.x;
  const int p = blockIdx.y;
  const int wave = threadIdx.x >> 6;
  const int lane = threadIdx.x & 63;
  const int col = lane & 15, quad = lane >> 4;
  const int h = kvh * 4 + wave;
  const ushort* qh = qbg + (size_t)h * S_LEN * HD;
  const ushort* kbase = kbg + (size_t)kvh * 32 * 4096;
  const ushort* vbase = vtg + (size_t)kvh * 32 * 4096;
  const int rsw = col & 7;  // bank-swizzle key

  auto stage = [&](int tile, int buf) {
#pragma unroll
    for (int g = 0; g < 2; ++g) {
      int gg = wave + g * 4;
      gld_lds16(kbase + (size_t)tile * 4096 + gg * 512 + lane * 8, &Ks[buf][gg * 512]);
      gld_lds16(vbase + (size_t)tile * 4096 + gg * 512 + lane * 8, &Vs[buf][gg * 512]);
    }
  };

  auto do_strip = [&](int s) {
    const int nt = (s >> 2) + 1;
    const int q0 = s * 16;
    bf16x8 qf[2];
    qf[0] = *(const bf16x8*)&qh[(size_t)(q0 + col) * HD + quad * 8];
    qf[1] = *(const bf16x8*)&qh[(size_t)(q0 + col) * HD + 32 + quad * 8];
    float l[4] = {};
    f32x4 o[4] = {};
    stage(0, 0);
    __syncthreads();
    for (int t = 0; t < nt; ++t) {
      const int buf = t & 1;
      if (t + 1 < nt) stage(t + 1, buf ^ 1);
      f32x4 sc[4] = {};
#pragma unroll
      for (int c = 0; c < 2; ++c) {
        const int chs = (c * 4 + quad) ^ rsw;
#pragma unroll
        for (int j = 0; j < 4; ++j) {
          bf16x8 kf = *(const bf16x8*)&Ks[buf][((j * 16 + col) * 8 + chs) * 8];
          sc[j] = __builtin_amdgcn_mfma_f32_16x16x32_bf16(qf[c], kf, sc[j], 0, 0, 0);
        }
      }
      const bool masked = (t == nt - 1);
#pragma unroll
      for (int r = 0; r < 4; ++r) {
        const int rowq = q0 + quad * 4 + r;
        float pr[4];
#pragma unroll
        for (int j = 0; j < 4; ++j) {
          float e = __builtin_amdgcn_exp2f(sc[j][r]);
          if (masked) e = (t * 64 + j * 16 + col > rowq) ? 0.f : e;
          pr[j] = e;
        }
        l[r] += (pr[0] + pr[1]) + (pr[2] + pr[3]);
        uint2 pk;
        pk.x = pack_bf2_rz(pr[0], pr[1]);
        pk.y = pack_bf2_rz(pr[2], pr[3]);
        *(uint2*)&Ps[wave][buf][quad * 4 + r][col * 4] = pk;
      }
#pragma unroll
      for (int c = 0; c < 2; ++c) {
        const int chs = (c * 4 + quad) ^ rsw;
        bf16x8 pf = *(const bf16x8*)&Ps[wave][buf][col][c * 32 + quad * 8];
#pragma unroll
        for (int db = 0; db < 4; ++db) {
          bf16x8 vf = *(const bf16x8*)&Vs[buf][((db * 16 + col) * 8 + chs) * 8];
          o[db] = __builtin_amdgcn_mfma_f32_16x16x32_bf16(pf, vf, o[db], 0, 0, 0);
        }
      }
      __syncthreads();
    }
#pragma unroll
    for (int r = 0; r < 4; ++r) {
      float ls = l[r];
      ls += __shfl_xor(ls, 1);
      ls += __shfl_xor(ls, 2);
      ls += __shfl_xor(ls, 4);
      ls += __shfl_xor(ls, 8);
      float inv = 1.0f / ls;
      int rowq = q0 + quad * 4 + r;
#pragma unroll
      for (int db = 0; db < 4; ++db)
        yb[(size_t)rowq * (NH * HD) + h * HD + db * 16 + col] = f2bf(o[db][r] * inv);
    }
  };

  do_strip(127 - p);
  do_strip(p);
}

extern "C" void kernel_launch(void* const* d_in, const int* in_sizes, int n_in,
                              void* d_out, int out_size, void* d_ws, size_t ws_size,
                              hipStream_t stream) {
  (void)in_sizes; (void)n_in; (void)out_size; (void)ws_size;
  const float* x  = (const float*)d_in[0];
  const float* fc = (const float*)d_in[1];
  const float* fs = (const float*)d_in[2];
  const float* wq = (const float*)d_in[4];
  const float* wk = (const float*)d_in[5];
  const float* wv = (const float*)d_in[6];
  const float* wo = (const float*)d_in[7];
  ushort* w = (ushort*)d_ws;
  const size_t M1 = 1024 * 1024;
  ushort* xb    = w;
  ushort* wqkvb = w + 4 * M1;
  ushort* wob   = w + 10 * M1;
  ushort* qkvb  = w + 14 * M1;
  ushort* qb    = w + 20 * M1;
  ushort* kb    = w + 24 * M1;
  ushort* vt    = w + 25 * M1;
  ushort* yb    = w + 26 * M1;

  convert_all<<<14336, 256, 0, stream>>>(x, wq, wk, wv, wo, xb, wqkvb, wob);
  gemm_bt<1><<<dim3(QKVF / 128, S_LEN / 128), 256, 0, stream>>>(xb, wqkvb, qkvb, S_LEN, QKVF, DIMN);
  rope_layout<<<dim3(48, 8), 256, 0, stream>>>(qkvb, fc, fs, qb, kb, vt);
  attn<<<dim3(NKV, 64), 256, 0, stream>>>(qb, kb, vt, yb);
  gemm_bt<0><<<dim3(DIMN / 128, S_LEN / 128), 256, 0, stream>>>(yb, wob, d_out, S_LEN, DIMN, NH * HD);
}